// Round 7
// baseline (38.170 us; speedup 1.0000x reference)
//
#include <hip/hip_runtime.h>
#include <stdint.h>

#define RANKS 8
#define MDIM 8192   // B*T*D / 1024 rows
#define KDIM 1024
#define NDIM 1024
#define BM 128
#define BN 128
#define BK 32
#define NT (KDIM / BK)   // 32
#define THREADS 256

typedef __bf16 bf16x8 __attribute__((ext_vector_type(8)));
typedef float f32x4 __attribute__((ext_vector_type(4)));

__device__ __forceinline__ unsigned short f2bf(float f) {
  union { float f; uint32_t u; } v; v.f = f;
  uint32_t u = v.u;
  u += 0x7FFFu + ((u >> 16) & 1u);   // round-to-nearest-even
  return (unsigned short)(u >> 16);
}

// Hamilton block tables
__constant__ int   c_comp[4][4] = {{0,1,2,3},{1,0,3,2},{2,3,0,1},{3,2,1,0}};
__constant__ float c_sign[4][4] = {{1.f,-1.f,-1.f,-1.f},
                                   {1.f, 1.f,-1.f, 1.f},
                                   {1.f, 1.f, 1.f,-1.f},
                                   {1.f,-1.f, 1.f, 1.f}};

// ---------------------------------------------------------------------------
// W[p][q] = sum_r H[r,k,s] * fB[r,j,i],  p = k*64+j, q = s*64+i.  bf16 out.
// ---------------------------------------------------------------------------
__global__ void build_W(const float* __restrict__ A, const float* __restrict__ fB,
                        unsigned short* __restrict__ W) {
  int idx = blockIdx.x * 256 + threadIdx.x;
  int p  = idx >> 8;
  int q4 = (idx & 255) << 2;
  int k = p >> 6, j = p & 63;
  int kb = k >> 2, ks = k & 3;
  int s = q4 >> 6;
  int sb = s >> 2, ss = s & 3;
  int   comp = c_comp[kb][sb];
  float sgn  = c_sign[kb][sb];
  float o0 = 0.f, o1 = 0.f, o2 = 0.f, o3 = 0.f;
  int i0 = q4 & 63;
#pragma unroll
  for (int r = 0; r < RANKS; ++r) {
    float h = sgn * A[r * 64 + comp * 16 + ks * 4 + ss];
    const float* fb = fB + r * 4096 + j * 64 + i0;
    o0 += h * fb[0]; o1 += h * fb[1]; o2 += h * fb[2]; o3 += h * fb[3];
  }
  ushort4 st;
  st.x = f2bf(o0); st.y = f2bf(o1); st.z = f2bf(o2); st.w = f2bf(o3);
  *reinterpret_cast<ushort4*>(W + (size_t)p * KDIM + q4) = st;
}

// ---------------------------------------------------------------------------
// Fused GEMM: out = bf16(x) * W^T + bias.
// R1's simple compiler-scheduled loop (one __syncthreads per tile) +
// fused f32-A via global_load_lds + 48 KB double-buffer -> 3 blocks/CU.
// A read-swizzle u^(r&7) (8x16B units/row); B read-swizzle u^((r>>1)&3)
// (4x16B units/row) with matching pre-swizzled global sources (rule 21).
// ---------------------------------------------------------------------------
__device__ __forceinline__ void gload16(const void* g, void* l) {
  __builtin_amdgcn_global_load_lds(
      (const __attribute__((address_space(1))) unsigned int*)(uintptr_t)g,
      (__attribute__((address_space(3))) unsigned int*)(uintptr_t)l,
      16, 0, 0);
}

__global__ __launch_bounds__(THREADS, 3) void gemm_ham(
    const float* __restrict__ x, const unsigned short* __restrict__ W,
    const float* __restrict__ bias, float* __restrict__ out) {
  __shared__ float          Asm_[2][BM * BK];   // f32: 16 KB/slot, 32 KB
  __shared__ unsigned short Bsm_[2][BN * BK];   // bf16: 8 KB/slot, 16 KB

  const int tid  = threadIdx.x;
  const int lane = tid & 63;
  const int wid  = tid >> 6;        // 0..3
  const int wr   = wid >> 1;        // 0..1 (M)
  const int wc   = wid & 1;         // 0..1 (N)
  const int rb   = lane & 15;
  const int qtr  = lane >> 4;       // 0..3

  // T1: XCD-chunked bijective swizzle over 512 blocks (8 XCDs x 64).
  const int flat = blockIdx.x;
  const int xg = flat & 7, ig = flat >> 3;     // ig: 0..63
  const int bx = xg * 8 + (ig >> 3);           // 0..63
  const int by = ig & 7;                       // 0..7
  const int row0 = bx * BM;
  const int col0 = by * BN;

  f32x4 acc[4][4];
  f32x4 zero = {0.f, 0.f, 0.f, 0.f};
#pragma unroll
  for (int m = 0; m < 4; ++m)
#pragma unroll
    for (int n = 0; n < 4; ++n) acc[m][n] = zero;

  // ---- async staging: linear LDS dest, inverse-swizzled global source -----
  auto stageA = [&](int kt, int slot) {
#pragma unroll
    for (int g = 0; g < 4; ++g) {
      int id = g * 256 + tid;        // 16B-unit id, 0..1023
      int r = id >> 3, ct = id & 7;
      gload16(x + (size_t)(row0 + r) * KDIM + kt * BK + ((ct ^ (r & 7)) << 2),
              &Asm_[slot][id * 4]);
    }
  };
  auto stageB = [&](int kt, int slot) {
#pragma unroll
    for (int g = 0; g < 2; ++g) {
      int id = g * 256 + tid;        // 0..511
      int r = id >> 2, ct = id & 3;
      gload16(W + (size_t)(col0 + r) * KDIM + kt * BK + ((ct ^ ((r >> 1) & 3)) << 3),
              &Bsm_[slot][id * 8]);
    }
  };

  // ---- prologue ------------------------------------------------------------
  stageA(0, 0); stageB(0, 0);
  __syncthreads();

  int cur = 0;
#pragma unroll 1
  for (int t = 0; t < NT; ++t) {
    if (t + 1 < NT) { stageA(t + 1, cur ^ 1); stageB(t + 1, cur ^ 1); }

    const char* Ab = reinterpret_cast<const char*>(&Asm_[cur][0]);
    const char* Bb = reinterpret_cast<const char*>(&Bsm_[cur][0]);
    bf16x8 af[4], bfr[4];
#pragma unroll
    for (int m = 0; m < 4; ++m) {
      int r = wr * 64 + m * 16 + rb;
      int u0 = (qtr * 2)     ^ (r & 7);
      int u1 = (qtr * 2 + 1) ^ (r & 7);
      f32x4 lo = *reinterpret_cast<const f32x4*>(Ab + r * 128 + (u0 << 4));
      f32x4 hi = *reinterpret_cast<const f32x4*>(Ab + r * 128 + (u1 << 4));
      bf16x8 v;
      v[0] = (__bf16)lo[0]; v[1] = (__bf16)lo[1]; v[2] = (__bf16)lo[2]; v[3] = (__bf16)lo[3];
      v[4] = (__bf16)hi[0]; v[5] = (__bf16)hi[1]; v[6] = (__bf16)hi[2]; v[7] = (__bf16)hi[3];
      af[m] = v;
    }
#pragma unroll
    for (int n = 0; n < 4; ++n) {
      int r = wc * 64 + n * 16 + rb;
      int u = qtr ^ ((r >> 1) & 3);
      bfr[n] = *reinterpret_cast<const bf16x8*>(Bb + r * 64 + (u << 4));
    }

#pragma unroll
    for (int m = 0; m < 4; ++m)
#pragma unroll
      for (int n = 0; n < 4; ++n)
        acc[m][n] = __builtin_amdgcn_mfma_f32_16x16x32_bf16(af[m], bfr[n], acc[m][n], 0, 0, 0);

    __syncthreads();
    cur ^= 1;
  }

  // ---- epilogue: C/D layout col=lane&15, row=(lane>>4)*4+reg --------------
  const int crow = row0 + wr * 64 + qtr * 4;
  const int ccol = col0 + wc * 64 + rb;
#pragma unroll
  for (int n = 0; n < 4; ++n) {
    int c = ccol + n * 16;
    float bv = bias[c];
#pragma unroll
    for (int m = 0; m < 4; ++m)
#pragma unroll
      for (int v = 0; v < 4; ++v)
        out[(size_t)(crow + m * 16 + v) * NDIM + c] = acc[m][n][v] + bv;
  }
}

// ---------------------------------------------------------------------------
// Workspace-free fallback (slow but correct)
// ---------------------------------------------------------------------------
__global__ void fallback_kernel(const float* __restrict__ x, const float* __restrict__ A,
                                const float* __restrict__ fB, const float* __restrict__ bias,
                                float* __restrict__ out) {
  __shared__ float xrow[1024];
  const int n = blockIdx.x;
  const int tid = threadIdx.x;
  for (int t = tid; t < 1024; t += 256) xrow[t] = x[(size_t)n * 1024 + t];
  __syncthreads();
  for (int pp = 0; pp < 4; ++pp) {
    int p = pp * 256 + tid;
    int k = p >> 6, j = p & 63;
    int kb = k >> 2, ks = k & 3;
    float accv = 0.f;
    for (int s = 0; s < 16; ++s) {
      int sb = s >> 2, ss = s & 3;
      int comp = c_comp[kb][sb];
      float sgn = c_sign[kb][sb];
      float hA[RANKS];
#pragma unroll
      for (int r = 0; r < RANKS; ++r) hA[r] = sgn * A[r * 64 + comp * 16 + ks * 4 + ss];
      for (int i = 0; i < 64; ++i) {
        float w = 0.f;
#pragma unroll
        for (int r = 0; r < RANKS; ++r) w += hA[r] * fB[r * 4096 + j * 64 + i];
        accv += xrow[s * 64 + i] * w;
      }
    }
    out[(size_t)n * 1024 + p] = accv + bias[p];
  }
}

extern "C" void kernel_launch(void* const* d_in, const int* in_sizes, int n_in,
                              void* d_out, int out_size, void* d_ws, size_t ws_size,
                              hipStream_t stream) {
  const float* x    = (const float*)d_in[0];
  const float* A    = (const float*)d_in[1];
  const float* fB   = (const float*)d_in[2];
  const float* bias = (const float*)d_in[3];
  float* out = (float*)d_out;

  const size_t needW = (size_t)NDIM * KDIM * sizeof(unsigned short);
  if (ws_size >= needW) {
    unsigned short* W = (unsigned short*)d_ws;
    build_W<<<dim3(1024), dim3(256), 0, stream>>>(A, fB, W);
    gemm_ham<<<dim3((MDIM / BM) * (NDIM / BN)), dim3(THREADS), 0, stream>>>(x, W, bias, out);
  } else {
    fallback_kernel<<<dim3(MDIM), dim3(256), 0, stream>>>(x, A, fB, bias, out);
  }
}